// Round 2
// baseline (209.195 us; speedup 1.0000x reference)
//
#include <hip/hip_runtime.h>

constexpr float ALPHA = 0.001f;
constexpr float BETA  = 0.001f;
constexpr int R   = 64;
constexpr int S   = 3;
constexpr int PFW = R * (1 + 2 * S); // 448 floats per pF row
constexpr int BUCKET_SHIFT = 7;      // 128 pF rows per bucket = 229 KB region

// ---------------- aux: histogram of i>>7 ----------------
__global__ __launch_bounds__(1024) void hist_kernel(const int* __restrict__ ijk, int B,
                                                    int* __restrict__ hist, int nb) {
    __shared__ int lh[1024];
    for (int t = threadIdx.x; t < nb; t += blockDim.x) lh[t] = 0;
    __syncthreads();
    for (long idx = (long)blockIdx.x * blockDim.x + threadIdx.x; idx < B;
         idx += (long)gridDim.x * blockDim.x) {
        int i = ijk[3 * idx];
        atomicAdd(&lh[i >> BUCKET_SHIFT], 1);
    }
    __syncthreads();
    for (int t = threadIdx.x; t < nb; t += blockDim.x)
        if (lh[t]) atomicAdd(&hist[t], lh[t]);
}

// ---------------- aux: exclusive scan (single block, nb <= 1024) ----------------
__global__ __launch_bounds__(1024) void scan_kernel(const int* __restrict__ hist,
                                                    int* __restrict__ offs, int nb) {
    __shared__ int buf[1024];
    int t = threadIdx.x;
    int own = (t < nb) ? hist[t] : 0;
    buf[t] = own;
    __syncthreads();
    for (int d = 1; d < 1024; d <<= 1) {
        int v = (t >= d) ? buf[t - d] : 0;
        __syncthreads();
        buf[t] += v;
        __syncthreads();
    }
    if (t < nb) offs[t] = buf[t] - own; // exclusive
}

// ---------------- aux: scatter b-indices into bucket order ----------------
__global__ __launch_bounds__(256) void scatter_kernel(const int* __restrict__ ijk, int B,
                                                      int* __restrict__ offs,
                                                      int* __restrict__ perm) {
    for (long idx = (long)blockIdx.x * blockDim.x + threadIdx.x; idx < B;
         idx += (long)gridDim.x * blockDim.x) {
        int i = ijk[3 * idx];
        int slot = atomicAdd(&offs[i >> BUCKET_SHIFT], 1);
        perm[slot] = (int)idx;
    }
}

// ---------------- main: 16 lanes per b, bucket-ordered, XCD-chunked ----------------
__global__ __launch_bounds__(256) void mf_if_kernel(
    const float* __restrict__ pF,
    const float* __restrict__ M,
    const int*   __restrict__ ijk,
    const int*   __restrict__ perm,   // may be null (fallback: identity)
    float* __restrict__ out,
    int B, int nwg)
{
    // bijective XCD-chunked swizzle (m204): contiguous bucket ranges -> one XCD
    const int orig = blockIdx.x;
    const int q = nwg >> 3, r = nwg & 7;
    const int xcd = orig & 7;
    const int wgid = (xcd < r ? xcd * (q + 1) : r * (q + 1) + (xcd - r) * q) + (orig >> 3);

    const int lane = threadIdx.x & 63;
    const int sub  = lane & 15;
    const long pos = (long)wgid * 16 + (threadIdx.x >> 4); // 16 groups per 256-thr block
    if (pos >= B) return;

    const int b = perm ? perm[pos] : (int)pos;

    const int i  = ijk[3 * b + 0];
    const int j  = ijk[3 * b + 1];
    const int k  = ijk[3 * b + 2];
    const int kc = (k < 0) ? 0 : k;

    const float4* pFi = reinterpret_cast<const float4*>(pF + (size_t)i * PFW);
    const float4* Mjp = reinterpret_cast<const float4*>(M + (size_t)j  * R);
    const float4* Mkp = reinterpret_cast<const float4*>(M + (size_t)kc * R);

    const float4 mj = Mjp[sub];
    const float4 mk = Mkp[sub];
    const float4 pi = pFi[sub];

    float p = pi.x * mj.x + pi.y * mj.y + pi.z * mj.z + pi.w * mj.w;

    const float4 v0 = pFi[16 + 3 * sub + 0];
    const float4 v1 = pFi[16 + 3 * sub + 1];
    const float4 v2 = pFi[16 + 3 * sub + 2];
    float a0 = v0.x * mj.x + v0.w * mj.y + v1.z * mj.z + v2.y * mj.w;
    float a1 = v0.y * mj.x + v1.x * mj.y + v1.w * mj.z + v2.z * mj.w;
    float a2 = v0.z * mj.x + v1.y * mj.y + v2.x * mj.z + v2.w * mj.w;

    const float4 w0 = pFi[64 + 3 * sub + 0];
    const float4 w1 = pFi[64 + 3 * sub + 1];
    const float4 w2 = pFi[64 + 3 * sub + 2];
    float g0 = w0.x * mk.x + w0.w * mk.y + w1.z * mk.z + w2.y * mk.w;
    float g1 = w0.y * mk.x + w1.x * mk.y + w1.w * mk.z + w2.z * mk.w;
    float g2 = w0.z * mk.x + w1.y * mk.y + w2.x * mk.z + w2.w * mk.w;

    #pragma unroll
    for (int off = 8; off >= 1; off >>= 1) {
        p  += __shfl_xor(p,  off);
        a0 += __shfl_xor(a0, off);
        a1 += __shfl_xor(a1, off);
        a2 += __shfl_xor(a2, off);
        g0 += __shfl_xor(g0, off);
        g1 += __shfl_xor(g1, off);
        g2 += __shfl_xor(g2, off);
    }

    if (sub == 0) {
        const float mfm = (k != -1)
            ? (BETA * BETA) * (a0 * g0 + a1 * g1 + a2 * g2)
            : 0.0f;
        out[b] = ALPHA * p + mfm;
    }
}

extern "C" void kernel_launch(void* const* d_in, const int* in_sizes, int n_in,
                              void* d_out, int out_size, void* d_ws, size_t ws_size,
                              hipStream_t stream) {
    const float* pF  = (const float*)d_in[0];
    const float* M   = (const float*)d_in[1];
    const int*   ijk = (const int*)d_in[2];
    float* out = (float*)d_out;

    const int B   = in_sizes[2] / 3;            // 500000
    const int N_P = in_sizes[0] / PFW;          // 100000
    const int nb  = (N_P + (1 << BUCKET_SHIFT) - 1) >> BUCKET_SHIFT; // 782

    const long total_threads = (long)B * 16;
    const int threads = 256;
    const int nwg = (int)((total_threads + threads - 1) / threads);

    // workspace layout: hist[1024] | offs[1024] | perm[B]
    const size_t need = (size_t)(2048 + B) * sizeof(int);
    int* perm = nullptr;
    if (ws_size >= need && nb <= 1024) {
        int* hist = (int*)d_ws;
        int* offs = hist + 1024;
        perm      = hist + 2048;

        hipMemsetAsync(hist, 0, 1024 * sizeof(int), stream);
        hist_kernel<<<128, 1024, 0, stream>>>(ijk, B, hist, nb);
        scan_kernel<<<1, 1024, 0, stream>>>(hist, offs, nb);
        scatter_kernel<<<1024, 256, 0, stream>>>(ijk, B, offs, perm);
    }

    mf_if_kernel<<<nwg, threads, 0, stream>>>(pF, M, ijk, perm, out, B, nwg);
}